// Round 4
// baseline (321.528 us; speedup 1.0000x reference)
//
#include <hip/hip_runtime.h>

#define PFEAT 58
#define S18   18
#define ENT   324   // 18*18

// p -> (row,col,factor) tables for _assemble (FLIST=[1,3,5], offs=[0,1,4])
__device__ __constant__ unsigned char c_row[PFEAT] = {
    0,0,0,0,0,0,0,0,0,
    1,1,1,2,2,2,3,3,3,
    1,1,1,1,1,2,2,2,2,2,3,3,3,3,3,
    4,4,4,4,4,5,5,5,5,5,6,6,6,6,6,7,7,7,7,7,8,8,8,8,8};
__device__ __constant__ unsigned char c_col[PFEAT] = {
    0,1,2,3,4,5,6,7,8,
    1,2,3,1,2,3,1,2,3,
    4,5,6,7,8,4,5,6,7,8,4,5,6,7,8,
    4,5,6,7,8,4,5,6,7,8,4,5,6,7,8,4,5,6,7,8,4,5,6,7,8};
__device__ __constant__ float c_fac[PFEAT] = {
    0.5f,1,1,1,1,1,1,1,1,
    0.5f,0.5f,0.5f,0.5f,0.5f,0.5f,0.5f,0.5f,0.5f,
    1,1,1,1,1,1,1,1,1,1,1,1,1,1,1,
    0.5f,0.5f,0.5f,0.5f,0.5f,0.5f,0.5f,0.5f,0.5f,0.5f,0.5f,0.5f,0.5f,
    0.5f,0.5f,0.5f,0.5f,0.5f,0.5f,0.5f,0.5f,0.5f,0.5f,0.5f,0.5f};

// int64-vs-int32 probe for edge_index (reference declares int64).
__device__ __forceinline__ bool detect_i64(const int* __restrict__ ei) {
    const uint2* p = (const uint2*)ei;
    unsigned acc = 0u;
#pragma unroll 8
    for (int m = 0; m < 64; ++m) acc |= p[m].y;
    return acc == 0u;
}

__device__ __forceinline__ int load_idx(const int* __restrict__ ei, int pos,
                                        bool is64, int A) {
    int v = is64 ? ei[2 * pos] : ei[pos];
    v = v < 0 ? 0 : (v >= A ? A - 1 : v);   // never fault on bad decode
    return v;
}

// Assemble 9x9 from feats, spin-double, rotate: sM = Rs * H18 * Rd^T.
__device__ __forceinline__ void assemble_rotate(
    const float* __restrict__ feat, const float* __restrict__ Rs,
    const float* __restrict__ Rd, float* sH9, float* sRs, float* sRd,
    float* sT, float* sM, int t, int nthreads)
{
    for (int idx = t; idx < ENT; idx += nthreads) { sRs[idx] = Rs[idx]; sRd[idx] = Rd[idx]; }
    if (t < 81) sH9[t] = 0.f;
    __syncthreads();
    if (t < PFEAT) sH9[c_row[t] * 9 + c_col[t]] = c_fac[t] * feat[t];
    __syncthreads();

    for (int idx = t; idx < ENT; idx += nthreads) {
        const int pp = idx / S18, q = idx - pp * S18;
        const int i = pp >> 1, u = pp & 1;
        float acc = 0.f;
#pragma unroll
        for (int j = 0; j < 9; ++j)
            acc += sH9[i * 9 + j] * sRd[q * S18 + 2 * j + u];
        sT[idx] = acc;
    }
    __syncthreads();

    for (int idx = t; idx < ENT; idx += nthreads) {
        const int p = idx / S18, q = idx - p * S18;
        float acc = 0.f;
#pragma unroll
        for (int pp = 0; pp < S18; ++pp)
            acc += sRs[p * S18 + pp] * sT[pp * S18 + q];
        sM[idx] = acc;
    }
}

// ---------------- CSR (write-once) path ----------------

__global__ __launch_bounds__(256) void zero_counts_kernel(int* __restrict__ cursor, int A)
{
    const int t = blockIdx.x * 256 + threadIdx.x;
    if (t < A) cursor[t] = 0;
}

__global__ __launch_bounds__(256) void count_kernel(
    const int* __restrict__ ei, int* __restrict__ cursor, int E, int A)
{
    __shared__ bool s64;
    if (threadIdx.x == 0) s64 = detect_i64(ei);
    __syncthreads();
    const int e = blockIdx.x * 256 + threadIdx.x;
    if (e < E) {
        const int a = load_idx(ei, e, s64, A);
        const int b = load_idx(ei, E + e, s64, A);
        atomicAdd(&cursor[a], 1);   // direct entry in row a
        atomicAdd(&cursor[b], 1);   // conj entry in row b
    }
}

__global__ __launch_bounds__(256) void scan_kernel(
    int* __restrict__ cursor, int* __restrict__ offsets, int A)
{
    if (threadIdx.x == 0) {
        int acc = 0;
        for (int a = 0; a < A; ++a) { offsets[a] = acc; acc += cursor[a]; }
        offsets[A] = acc;
    }
    __syncthreads();
    for (int a = threadIdx.x; a < A; a += 256) cursor[a] = offsets[a];
}

__global__ __launch_bounds__(256) void fill_kernel(
    const int* __restrict__ ei, int* __restrict__ cursor,
    int2* __restrict__ entries, int E, int A)
{
    __shared__ bool s64;
    if (threadIdx.x == 0) s64 = detect_i64(ei);
    __syncthreads();
    const int e = blockIdx.x * 256 + threadIdx.x;
    if (e < E) {
        const int a = load_idx(ei, e, s64, A);
        const int b = load_idx(ei, E + e, s64, A);
        const int p = atomicAdd(&cursor[a], 1);
        entries[p] = make_int2(e, b);                 // direct: row a, col-block b
        const int q = atomicAdd(&cursor[b], 1);
        entries[q] = make_int2(e | (1 << 30), a);     // conj:   row b, col-block a
    }
}

// One block per item: [0,E) edges -> hop_rot, [E,E+A) atoms -> ons_rot.
__global__ __launch_bounds__(128) void rotate_kernel(
    const float* __restrict__ hop_feat, const float* __restrict__ ons_feat,
    const float* __restrict__ R, const int* __restrict__ ei,
    float* __restrict__ hop_rot, float* __restrict__ ons_rot, int E, int A)
{
    __shared__ float sH9[81];
    __shared__ float sRs[ENT];
    __shared__ float sRd[ENT];
    __shared__ float sT[ENT];
    __shared__ bool  s64;

    const int item = blockIdx.x;
    const int t = threadIdx.x;
    if (t == 0) s64 = detect_i64(ei);
    __syncthreads();

    const float* feat; const float* Rs; const float* Rd; float* outp;
    if (item < E) {
        const int a_s = load_idx(ei, item, s64, A);
        const int a_d = load_idx(ei, E + item, s64, A);
        feat = hop_feat + (size_t)item * PFEAT;
        Rs = R + (size_t)a_s * ENT;
        Rd = R + (size_t)a_d * ENT;
        outp = hop_rot + (size_t)item * ENT;
    } else {
        const int a = item - E;
        feat = ons_feat + (size_t)a * PFEAT;
        Rs = R + (size_t)a * ENT;
        Rd = Rs;
        outp = ons_rot + (size_t)a * ENT;
    }
    // inline assemble_rotate with output to global (sM -> outp)
    for (int idx = t; idx < ENT; idx += 128) { sRs[idx] = Rs[idx]; sRd[idx] = Rd[idx]; }
    if (t < 81) sH9[t] = 0.f;
    __syncthreads();
    if (t < PFEAT) sH9[c_row[t] * 9 + c_col[t]] = c_fac[t] * feat[t];
    __syncthreads();
    for (int idx = t; idx < ENT; idx += 128) {
        const int pp = idx / S18, q = idx - pp * S18;
        const int i = pp >> 1, u = pp & 1;
        float acc = 0.f;
#pragma unroll
        for (int j = 0; j < 9; ++j)
            acc += sH9[i * 9 + j] * sRd[q * S18 + 2 * j + u];
        sT[idx] = acc;
    }
    __syncthreads();
    for (int idx = t; idx < ENT; idx += 128) {
        const int p = idx / S18, q = idx - p * S18;
        float acc = 0.f;
#pragma unroll
        for (int pp = 0; pp < S18; ++pp)
            acc += sRs[p * S18 + pp] * sT[pp * S18 + q];
        outp[idx] = acc;
    }
}

// One block per output row (I = a*18+i) per k. Accumulates the full row in
// LDS (sparse contributions via LDS atomics), then streams it out coalesced.
// Every output element written exactly once.
__global__ __launch_bounds__(256) void write_kernel(
    const float* __restrict__ hop_rot,    // [E,324]
    const float* __restrict__ ons_rot,    // [A,324]
    const int*   __restrict__ offsets,    // [A+1]
    const int2*  __restrict__ entries,    // [2E]
    const float* __restrict__ kpts,       // [K,3]
    const float* __restrict__ shift,      // [E,3]
    float* __restrict__ outf,
    int A, int K, int cplx, long long lim)
{
    extern __shared__ float rowbuf[];     // 2*N floats (interleaved complex)
    const int N = A * S18;
    const int I = blockIdx.x;
    const int k = blockIdx.y;
    const int t = threadIdx.x;
    const int a = I / S18, i = I - a * S18;
    const int n2 = 2 * N;

    for (int idx = t; idx < n2; idx += 256) rowbuf[idx] = 0.f;
    __syncthreads();

    // onsite: real(O + O^T) onto diagonal block (single writer per col)
    if (t < S18) {
        const float v = ons_rot[a * ENT + i * S18 + t] + ons_rot[a * ENT + t * S18 + i];
        rowbuf[2 * (a * S18 + t)] = v;
    }
    __syncthreads();

    const float kx = kpts[k * 3 + 0], ky = kpts[k * 3 + 1], kz = kpts[k * 3 + 2];
    const int beg = offsets[a], end = offsets[a + 1];
    const int g = t / S18, l = t - g * S18;   // 14 groups of 18 lanes
    if (g < 14) {
        for (int n = beg + g; n < end; n += 14) {
            const int2 ent = entries[n];
            const int conjf = (ent.x >> 30) & 1;
            const int e = ent.x & 0x3FFFFFFF;
            const int b = ent.y;
            const float dot = kx * shift[3 * e + 0] + ky * shift[3 * e + 1]
                            + kz * shift[3 * e + 2];
            float sv, cv;
            sincosf(-6.28318530717958647692f * dot, &sv, &cv);
            // direct (src=a,dst=b): out[I, b*18+l] += M[i][l] * (cv + i*sv)
            // conj (edge src=b,dst=a): out[I, b*18+l] += M[l][i] * (cv - i*sv)
            const float v = conjf ? hop_rot[(size_t)e * ENT + l * S18 + i]
                                  : hop_rot[(size_t)e * ENT + i * S18 + l];
            const float re = v * cv;
            const float im = conjf ? -v * sv : v * sv;
            atomicAdd(&rowbuf[2 * (b * S18 + l) + 0], re);
            atomicAdd(&rowbuf[2 * (b * S18 + l) + 1], im);
        }
    }
    __syncthreads();

    const long long base = ((long long)k * N + I) * (long long)N;  // complex idx
    if (cplx) {
        float* dst = outf + 2 * base;
        if (2 * base + n2 <= lim) {
            const float4* s4 = (const float4*)rowbuf;
            float4* d4 = (float4*)dst;
            const int nv = n2 >> 2;
            for (int idx = t; idx < nv; idx += 256) d4[idx] = s4[idx];
        } else {
            for (int idx = t; idx < n2; idx += 256)
                if (2 * base + idx < lim) dst[idx] = rowbuf[idx];
        }
    } else {
        float* dst = outf + base;
        if (base + N <= lim) {
            for (int c = t; c < N; c += 256) dst[c] = rowbuf[2 * c];
        } else {
            for (int c = t; c < N; c += 256)
                if (base + c < lim) dst[c] = rowbuf[2 * c];
        }
    }
}

// ---------------- fallback (R3 atomic) path ----------------

__global__ __launch_bounds__(256) void zero_kernel(float* __restrict__ p, long long n)
{
    const long long i4 = ((long long)blockIdx.x * 256 + threadIdx.x) * 4;
    if (i4 + 3 < n) {
        *(float4*)(p + i4) = make_float4(0.f, 0.f, 0.f, 0.f);
    } else if (i4 < n) {
        for (long long i = i4; i < n; ++i) p[i] = 0.f;
    }
}

__global__ __launch_bounds__(256) void edge_kernel(
    const float* __restrict__ hop_feat, const float* __restrict__ R,
    const float* __restrict__ kpts, const float* __restrict__ shift,
    const int* __restrict__ edge_index, float* __restrict__ outf,
    int E, int A, int K, int cplx, long long lim)
{
    __shared__ float sH9[81];
    __shared__ float sRs[ENT];
    __shared__ float sRd[ENT];
    __shared__ float sT[ENT];
    __shared__ float sM[ENT];
    __shared__ float sC[8];
    __shared__ float sS[8];

    const int e = blockIdx.x;
    const int t = threadIdx.x;
    const int N = A * S18;
    const long long N2 = (long long)N * N;

    const bool is64 = detect_i64(edge_index);
    const int a = load_idx(edge_index, e, is64, A);
    const int b = load_idx(edge_index, E + e, is64, A);

    if (t < K && t < 8) {
        const float sx = shift[e * 3 + 0], sy = shift[e * 3 + 1], sz = shift[e * 3 + 2];
        const float dot = kpts[t * 3 + 0] * sx + kpts[t * 3 + 1] * sy + kpts[t * 3 + 2] * sz;
        float sv, cv;
        sincosf(-6.28318530717958647692f * dot, &sv, &cv);
        sC[t] = cv; sS[t] = sv;
    }

    assemble_rotate(hop_feat + (size_t)e * PFEAT,
                    R + (size_t)a * ENT, R + (size_t)b * ENT,
                    sH9, sRs, sRd, sT, sM, t, 256);
    __syncthreads();

    const int total = K * ENT;
    for (int idx = t; idx < total; idx += 256) {
        const int k = idx / ENT, r = idx - k * ENT;
        const int i = r / S18, j = r - i * S18;
        const float v = sM[r];
        const float re = v * sC[k];
        const float im = v * sS[k];
        const long long I = (long long)a * S18 + i;
        const long long J = (long long)b * S18 + j;
        const long long p1 = k * N2 + I * N + J;
        const long long p2 = k * N2 + J * N + I;
        if (cplx) {
            if (2 * p1 + 1 < lim) { atomicAdd(&outf[2 * p1], re); atomicAdd(&outf[2 * p1 + 1], im); }
            if (2 * p2 + 1 < lim) { atomicAdd(&outf[2 * p2], re); atomicAdd(&outf[2 * p2 + 1], -im); }
        } else {
            if (p1 < lim) atomicAdd(&outf[p1], re);
            if (p2 < lim) atomicAdd(&outf[p2], re);
        }
    }
}

__global__ __launch_bounds__(128) void onsite_kernel(
    const float* __restrict__ ons_feat, const float* __restrict__ R,
    float* __restrict__ outf, int A, int K, int cplx, long long lim)
{
    __shared__ float sH9[81];
    __shared__ float sRs[ENT];
    __shared__ float sRd[ENT];
    __shared__ float sT[ENT];
    __shared__ float sM[ENT];

    const int a = blockIdx.x;
    const int t = threadIdx.x;
    const int N = A * S18;
    const long long N2 = (long long)N * N;

    assemble_rotate(ons_feat + (size_t)a * PFEAT,
                    R + (size_t)a * ENT, R + (size_t)a * ENT,
                    sH9, sRs, sRd, sT, sM, t, 128);
    __syncthreads();

    for (int idx = t; idx < ENT; idx += 128) {
        const int i = idx / S18, j = idx - (idx / S18) * S18;
        const float v = sM[i * S18 + j] + sM[j * S18 + i];
        const long long I = (long long)a * S18 + i;
        const long long J = (long long)a * S18 + j;
        for (int k = 0; k < K; ++k) {
            const long long p1 = k * N2 + I * N + J;
            const long long off = cplx ? 2 * p1 : p1;
            if (off < lim) outf[off] += v;
        }
    }
}

extern "C" void kernel_launch(void* const* d_in, const int* in_sizes, int n_in,
                              void* d_out, int out_size, void* d_ws, size_t ws_size,
                              hipStream_t stream) {
    const float* hop_feat   = (const float*)d_in[0];
    const float* ons_feat   = (const float*)d_in[1];
    const float* R          = (const float*)d_in[2];
    const float* kpts       = (const float*)d_in[3];
    const float* shift      = (const float*)d_in[4];
    const int*   edge_index = (const int*)d_in[5];

    const int E = in_sizes[0] / PFEAT;   // 3072
    const int A = in_sizes[1] / PFEAT;   // 192
    const int K = in_sizes[3] / 3;       // 4

    const long long N  = (long long)A * S18;
    const long long n_real = (long long)K * N * N;
    const long long lim = (long long)out_size;
    const int cplx = (lim >= 2 * n_real) ? 1 : 0;

    float* outf = (float*)d_out;

    // workspace layout (8B-aligned throughout)
    char* ws = (char*)d_ws;
    const size_t off_hop = 0;
    const size_t off_ons = off_hop + (size_t)E * ENT * 4;
    const size_t off_ent = off_ons + (size_t)A * ENT * 4;
    const size_t off_off = off_ent + (size_t)2 * E * 8;
    const size_t off_cur = off_off + (size_t)(A + 1) * 4;
    const size_t needed  = off_cur + (size_t)A * 4;

    if (ws_size >= needed) {
        float* hop_rot = (float*)(ws + off_hop);
        float* ons_rot = (float*)(ws + off_ons);
        int2*  entries = (int2*)(ws + off_ent);
        int*   offsets = (int*)(ws + off_off);
        int*   cursor  = (int*)(ws + off_cur);

        zero_counts_kernel<<<(A + 255) / 256, 256, 0, stream>>>(cursor, A);
        count_kernel<<<(E + 255) / 256, 256, 0, stream>>>(edge_index, cursor, E, A);
        scan_kernel<<<1, 256, 0, stream>>>(cursor, offsets, A);
        fill_kernel<<<(E + 255) / 256, 256, 0, stream>>>(edge_index, cursor, entries, E, A);
        rotate_kernel<<<E + A, 128, 0, stream>>>(hop_feat, ons_feat, R, edge_index,
                                                 hop_rot, ons_rot, E, A);
        const size_t shmem = (size_t)2 * N * sizeof(float);
        dim3 grid((unsigned)N, (unsigned)K);
        write_kernel<<<grid, 256, shmem, stream>>>(hop_rot, ons_rot, offsets, entries,
                                                   kpts, shift, outf, A, K, cplx, lim);
    } else {
        const long long n4 = (lim + 3) / 4;
        const int zgrid = (int)((n4 + 255) / 256);
        zero_kernel<<<zgrid, 256, 0, stream>>>(outf, lim);
        edge_kernel<<<E, 256, 0, stream>>>(hop_feat, R, kpts, shift, edge_index,
                                           outf, E, A, K, cplx, lim);
        onsite_kernel<<<A, 128, 0, stream>>>(ons_feat, R, outf, A, K, cplx, lim);
    }
}

// Round 5
// 258.551 us; speedup vs baseline: 1.2436x; 1.2436x over previous
//
#include <hip/hip_runtime.h>

#define PFEAT 58
#define S18   18
#define ENT   324   // 18*18
#define MAXE  128   // max staged CSR entries per row (avg degree ~32)

// p -> (row,col,factor) tables for _assemble (FLIST=[1,3,5], offs=[0,1,4])
__device__ __constant__ unsigned char c_row[PFEAT] = {
    0,0,0,0,0,0,0,0,0,
    1,1,1,2,2,2,3,3,3,
    1,1,1,1,1,2,2,2,2,2,3,3,3,3,3,
    4,4,4,4,4,5,5,5,5,5,6,6,6,6,6,7,7,7,7,7,8,8,8,8,8};
__device__ __constant__ unsigned char c_col[PFEAT] = {
    0,1,2,3,4,5,6,7,8,
    1,2,3,1,2,3,1,2,3,
    4,5,6,7,8,4,5,6,7,8,4,5,6,7,8,
    4,5,6,7,8,4,5,6,7,8,4,5,6,7,8,4,5,6,7,8,4,5,6,7,8};
__device__ __constant__ float c_fac[PFEAT] = {
    0.5f,1,1,1,1,1,1,1,1,
    0.5f,0.5f,0.5f,0.5f,0.5f,0.5f,0.5f,0.5f,0.5f,
    1,1,1,1,1,1,1,1,1,1,1,1,1,1,1,
    0.5f,0.5f,0.5f,0.5f,0.5f,0.5f,0.5f,0.5f,0.5f,0.5f,0.5f,0.5f,0.5f,
    0.5f,0.5f,0.5f,0.5f,0.5f,0.5f,0.5f,0.5f,0.5f,0.5f,0.5f,0.5f};

// int64-vs-int32 probe for edge_index (reference declares int64).
__device__ __forceinline__ bool detect_i64(const int* __restrict__ ei) {
    const uint2* p = (const uint2*)ei;
    unsigned acc = 0u;
#pragma unroll 8
    for (int m = 0; m < 64; ++m) acc |= p[m].y;
    return acc == 0u;
}

__device__ __forceinline__ int load_idx(const int* __restrict__ ei, int pos,
                                        bool is64, int A) {
    int v = is64 ? ei[2 * pos] : ei[pos];
    v = v < 0 ? 0 : (v >= A ? A - 1 : v);   // never fault on bad decode
    return v;
}

// Assemble 9x9 from feats, spin-double, rotate: sM = Rs * H18 * Rd^T.
__device__ __forceinline__ void assemble_rotate(
    const float* __restrict__ feat, const float* __restrict__ Rs,
    const float* __restrict__ Rd, float* sH9, float* sRs, float* sRd,
    float* sT, float* sM, int t, int nthreads)
{
    for (int idx = t; idx < ENT; idx += nthreads) { sRs[idx] = Rs[idx]; sRd[idx] = Rd[idx]; }
    if (t < 81) sH9[t] = 0.f;
    __syncthreads();
    if (t < PFEAT) sH9[c_row[t] * 9 + c_col[t]] = c_fac[t] * feat[t];
    __syncthreads();

    for (int idx = t; idx < ENT; idx += nthreads) {
        const int pp = idx / S18, q = idx - pp * S18;
        const int i = pp >> 1, u = pp & 1;
        float acc = 0.f;
#pragma unroll
        for (int j = 0; j < 9; ++j)
            acc += sH9[i * 9 + j] * sRd[q * S18 + 2 * j + u];
        sT[idx] = acc;
    }
    __syncthreads();

    for (int idx = t; idx < ENT; idx += nthreads) {
        const int p = idx / S18, q = idx - p * S18;
        float acc = 0.f;
#pragma unroll
        for (int pp = 0; pp < S18; ++pp)
            acc += sRs[p * S18 + pp] * sT[pp * S18 + q];
        sM[idx] = acc;
    }
}

// ---------------- CSR (write-once) path ----------------

// Single-block CSR build: count -> scan -> fill, all in LDS.
__global__ __launch_bounds__(256) void build_csr_kernel(
    const int* __restrict__ ei, int E, int A,
    int* __restrict__ offsets,   // [A+1]
    int2* __restrict__ entries)  // [2E]
{
    extern __shared__ int smem[];   // 2*A ints
    int* scnt = smem;
    int* scur = smem + A;
    __shared__ int sflag;
    const int t = threadIdx.x;
    if (t == 0) sflag = detect_i64(ei) ? 1 : 0;
    for (int a = t; a < A; a += 256) scnt[a] = 0;
    __syncthreads();
    const bool s64 = sflag != 0;
    for (int e = t; e < E; e += 256) {
        const int a = load_idx(ei, e, s64, A);
        const int b = load_idx(ei, E + e, s64, A);
        atomicAdd(&scnt[a], 1);
        atomicAdd(&scnt[b], 1);
    }
    __syncthreads();
    if (t == 0) {
        int acc = 0;
        for (int a = 0; a < A; ++a) { scur[a] = acc; acc += scnt[a]; }
    }
    __syncthreads();
    for (int a = t; a < A; a += 256) offsets[a] = scur[a];
    if (t == 0) offsets[A] = scur[A - 1] + scnt[A - 1];
    __syncthreads();
    for (int e = t; e < E; e += 256) {
        const int a = load_idx(ei, e, s64, A);
        const int b = load_idx(ei, E + e, s64, A);
        const int p = atomicAdd(&scur[a], 1);
        entries[p] = make_int2(e, b);                 // direct: row-atom a, col-block b
        const int q = atomicAdd(&scur[b], 1);
        entries[q] = make_int2(e | (1 << 30), a);     // conj:   row-atom b, col-block a
    }
}

// Per-(edge,k) Bloch phase table.
__global__ __launch_bounds__(256) void phase_kernel(
    const float* __restrict__ kpts, const float* __restrict__ shift,
    float* __restrict__ pcos, float* __restrict__ psin, int E, int K)
{
    const int idx = blockIdx.x * 256 + threadIdx.x;
    if (idx >= E * K) return;
    const int e = idx / K, k = idx - e * K;
    const float dot = kpts[k * 3 + 0] * shift[3 * e + 0]
                    + kpts[k * 3 + 1] * shift[3 * e + 1]
                    + kpts[k * 3 + 2] * shift[3 * e + 2];
    float sv, cv;
    sincosf(-6.28318530717958647692f * dot, &sv, &cv);
    pcos[idx] = cv;
    psin[idx] = sv;
}

// One block per item: [0,E) edges -> hop_rot (+ optional transpose),
// [E,E+A) atoms -> ons_rot.
__global__ __launch_bounds__(128) void rotate_kernel(
    const float* __restrict__ hop_feat, const float* __restrict__ ons_feat,
    const float* __restrict__ R, const int* __restrict__ ei,
    float* __restrict__ hop_rot, float* __restrict__ hop_rotT,
    float* __restrict__ ons_rot, int E, int A, int hasT)
{
    __shared__ float sH9[81];
    __shared__ float sRs[ENT];
    __shared__ float sRd[ENT];
    __shared__ float sT[ENT];
    __shared__ float sM[ENT];
    __shared__ int   sflag;

    const int item = blockIdx.x;
    const int t = threadIdx.x;
    if (t == 0) sflag = detect_i64(ei) ? 1 : 0;
    __syncthreads();
    const bool s64 = sflag != 0;

    const float* feat; const float* Rs; const float* Rd; float* outp;
    if (item < E) {
        const int a_s = load_idx(ei, item, s64, A);
        const int a_d = load_idx(ei, E + item, s64, A);
        feat = hop_feat + (size_t)item * PFEAT;
        Rs = R + (size_t)a_s * ENT;
        Rd = R + (size_t)a_d * ENT;
        outp = hop_rot + (size_t)item * ENT;
    } else {
        const int a = item - E;
        feat = ons_feat + (size_t)a * PFEAT;
        Rs = R + (size_t)a * ENT;
        Rd = Rs;
        outp = ons_rot + (size_t)a * ENT;
    }

    assemble_rotate(feat, Rs, Rd, sH9, sRs, sRd, sT, sM, t, 128);
    __syncthreads();

    for (int idx = t; idx < ENT; idx += 128) outp[idx] = sM[idx];
    if (item < E && hasT) {
        float* outpT = hop_rotT + (size_t)item * ENT;
        for (int idx = t; idx < ENT; idx += 128) {
            const int p = idx / S18, q = idx - p * S18;
            outpT[idx] = sM[q * S18 + p];   // T[p][q] = M[q][p]
        }
    }
}

// One block per output row (I = a*18+i) per k. Accumulates the row in LDS
// (real-only when cplx=0), then streams it out coalesced, write-once.
__global__ __launch_bounds__(256) void write_kernel(
    const float* __restrict__ hop_rot,    // [E,324]
    const float* __restrict__ hop_rotT,   // [E,324] transposed (optional)
    const float* __restrict__ ons_rot,    // [A,324]
    const int*   __restrict__ offsets,    // [A+1]
    const int2*  __restrict__ entries,    // [2E]
    const float* __restrict__ pcos,       // [E,K]
    const float* __restrict__ psin,       // [E,K]
    float* __restrict__ outf,
    int A, int K, int cplx, int hasT, long long lim)
{
    extern __shared__ float rowbuf[];     // (cplx?2:1)*N floats
    __shared__ int2  sent[MAXE];
    __shared__ float sphc[MAXE];
    __shared__ float sphs[MAXE];

    const int N = A * S18;
    const int I = blockIdx.x;
    const int k = blockIdx.y;
    const int t = threadIdx.x;
    const int a = I / S18, i = I - a * S18;
    const int stride = cplx ? 2 : 1;
    const int nbuf = stride * N;

    for (int idx = t; idx < nbuf; idx += 256) rowbuf[idx] = 0.f;

    const int beg = offsets[a], end = offsets[a + 1];
    const int cnt = end - beg;
    const int nst = cnt < MAXE ? cnt : MAXE;
    for (int n = t; n < nst; n += 256) {
        const int2 ent = entries[beg + n];
        sent[n] = ent;
        const int e0 = ent.x & 0x3FFFFFFF;
        sphc[n] = pcos[e0 * K + k];
        if (cplx) sphs[n] = psin[e0 * K + k];
    }
    __syncthreads();

    // onsite: real(O + O^T) onto diagonal block
    if (t < S18) {
        const float v = ons_rot[a * ENT + i * S18 + t] + ons_rot[a * ENT + t * S18 + i];
        atomicAdd(&rowbuf[stride * (a * S18 + t)], v);
    }

    // flat (entry, col) work distribution
    const int total = cnt * S18;
    for (int m = t; m < total; m += 256) {
        const int n = m / S18, l = m - n * S18;
        int2 ent; float pc, ps = 0.f;
        if (n < MAXE) {
            ent = sent[n]; pc = sphc[n]; if (cplx) ps = sphs[n];
        } else {
            ent = entries[beg + n];
            const int e0 = ent.x & 0x3FFFFFFF;
            pc = pcos[e0 * K + k]; if (cplx) ps = psin[e0 * K + k];
        }
        const int conjf = (ent.x >> 30) & 1;
        const int e = ent.x & 0x3FFFFFFF;
        const int b = ent.y;
        float v;
        if (!conjf)     v = hop_rot [(size_t)e * ENT + i * S18 + l];   // M[i][l]
        else if (hasT)  v = hop_rotT[(size_t)e * ENT + i * S18 + l];   // M^T[i][l] = M[l][i]
        else            v = hop_rot [(size_t)e * ENT + l * S18 + i];   // M[l][i]
        atomicAdd(&rowbuf[stride * (b * S18 + l)], v * pc);
        if (cplx)
            atomicAdd(&rowbuf[stride * (b * S18 + l) + 1], conjf ? -v * ps : v * ps);
    }
    __syncthreads();

    const long long base = (long long)stride * ((long long)k * N + I) * (long long)N;
    float* dst = outf + base;
    if (base + nbuf <= lim && (nbuf & 3) == 0) {
        const float4* s4 = (const float4*)rowbuf;
        float4* d4 = (float4*)dst;
        const int nv = nbuf >> 2;
        for (int idx = t; idx < nv; idx += 256) d4[idx] = s4[idx];
    } else {
        for (int idx = t; idx < nbuf; idx += 256)
            if (base + idx < lim) dst[idx] = rowbuf[idx];
    }
}

// ---------------- fallback (R3 atomic) path ----------------

__global__ __launch_bounds__(256) void zero_kernel(float* __restrict__ p, long long n)
{
    const long long i4 = ((long long)blockIdx.x * 256 + threadIdx.x) * 4;
    if (i4 + 3 < n) {
        *(float4*)(p + i4) = make_float4(0.f, 0.f, 0.f, 0.f);
    } else if (i4 < n) {
        for (long long i = i4; i < n; ++i) p[i] = 0.f;
    }
}

__global__ __launch_bounds__(256) void edge_kernel(
    const float* __restrict__ hop_feat, const float* __restrict__ R,
    const float* __restrict__ kpts, const float* __restrict__ shift,
    const int* __restrict__ edge_index, float* __restrict__ outf,
    int E, int A, int K, int cplx, long long lim)
{
    __shared__ float sH9[81];
    __shared__ float sRs[ENT];
    __shared__ float sRd[ENT];
    __shared__ float sT[ENT];
    __shared__ float sM[ENT];
    __shared__ float sC[8];
    __shared__ float sS[8];

    const int e = blockIdx.x;
    const int t = threadIdx.x;
    const int N = A * S18;
    const long long N2 = (long long)N * N;

    const bool is64 = detect_i64(edge_index);
    const int a = load_idx(edge_index, e, is64, A);
    const int b = load_idx(edge_index, E + e, is64, A);

    if (t < K && t < 8) {
        const float sx = shift[e * 3 + 0], sy = shift[e * 3 + 1], sz = shift[e * 3 + 2];
        const float dot = kpts[t * 3 + 0] * sx + kpts[t * 3 + 1] * sy + kpts[t * 3 + 2] * sz;
        float sv, cv;
        sincosf(-6.28318530717958647692f * dot, &sv, &cv);
        sC[t] = cv; sS[t] = sv;
    }

    assemble_rotate(hop_feat + (size_t)e * PFEAT,
                    R + (size_t)a * ENT, R + (size_t)b * ENT,
                    sH9, sRs, sRd, sT, sM, t, 256);
    __syncthreads();

    const int total = K * ENT;
    for (int idx = t; idx < total; idx += 256) {
        const int k = idx / ENT, r = idx - k * ENT;
        const int i = r / S18, j = r - i * S18;
        const float v = sM[r];
        const float re = v * sC[k];
        const float im = v * sS[k];
        const long long I = (long long)a * S18 + i;
        const long long J = (long long)b * S18 + j;
        const long long p1 = k * N2 + I * N + J;
        const long long p2 = k * N2 + J * N + I;
        if (cplx) {
            if (2 * p1 + 1 < lim) { atomicAdd(&outf[2 * p1], re); atomicAdd(&outf[2 * p1 + 1], im); }
            if (2 * p2 + 1 < lim) { atomicAdd(&outf[2 * p2], re); atomicAdd(&outf[2 * p2 + 1], -im); }
        } else {
            if (p1 < lim) atomicAdd(&outf[p1], re);
            if (p2 < lim) atomicAdd(&outf[p2], re);
        }
    }
}

__global__ __launch_bounds__(128) void onsite_kernel(
    const float* __restrict__ ons_feat, const float* __restrict__ R,
    float* __restrict__ outf, int A, int K, int cplx, long long lim)
{
    __shared__ float sH9[81];
    __shared__ float sRs[ENT];
    __shared__ float sRd[ENT];
    __shared__ float sT[ENT];
    __shared__ float sM[ENT];

    const int a = blockIdx.x;
    const int t = threadIdx.x;
    const int N = A * S18;
    const long long N2 = (long long)N * N;

    assemble_rotate(ons_feat + (size_t)a * PFEAT,
                    R + (size_t)a * ENT, R + (size_t)a * ENT,
                    sH9, sRs, sRd, sT, sM, t, 128);
    __syncthreads();

    for (int idx = t; idx < ENT; idx += 128) {
        const int i = idx / S18, j = idx - (idx / S18) * S18;
        const float v = sM[i * S18 + j] + sM[j * S18 + i];
        const long long I = (long long)a * S18 + i;
        const long long J = (long long)a * S18 + j;
        for (int k = 0; k < K; ++k) {
            const long long p1 = k * N2 + I * N + J;
            const long long off = cplx ? 2 * p1 : p1;
            if (off < lim) outf[off] += v;
        }
    }
}

extern "C" void kernel_launch(void* const* d_in, const int* in_sizes, int n_in,
                              void* d_out, int out_size, void* d_ws, size_t ws_size,
                              hipStream_t stream) {
    const float* hop_feat   = (const float*)d_in[0];
    const float* ons_feat   = (const float*)d_in[1];
    const float* R          = (const float*)d_in[2];
    const float* kpts       = (const float*)d_in[3];
    const float* shift      = (const float*)d_in[4];
    const int*   edge_index = (const int*)d_in[5];

    const int E = in_sizes[0] / PFEAT;   // 3072
    const int A = in_sizes[1] / PFEAT;   // 192
    const int K = in_sizes[3] / 3;       // 4

    const long long N  = (long long)A * S18;
    const long long n_real = (long long)K * N * N;
    const long long lim = (long long)out_size;
    const int cplx = (lim >= 2 * n_real) ? 1 : 0;

    float* outf = (float*)d_out;

    // workspace layout (all offsets 8B-aligned: ENT*4=1296 is 8-divisible)
    char* ws = (char*)d_ws;
    const size_t off_hop = 0;
    const size_t off_ons = off_hop + (size_t)E * ENT * 4;
    const size_t off_ent = off_ons + (size_t)A * ENT * 4;
    const size_t off_off = off_ent + (size_t)2 * E * 8;
    const size_t off_pc  = off_off + (size_t)(A + 2) * 4;
    const size_t off_ps  = off_pc  + (size_t)E * K * 4;
    const size_t base_need = off_ps + (size_t)E * K * 4;
    const size_t off_hT  = base_need;
    const size_t full_need = off_hT + (size_t)E * ENT * 4;

    if (ws_size >= base_need && A <= 4096) {
        const int hasT = (ws_size >= full_need) ? 1 : 0;
        float* hop_rot  = (float*)(ws + off_hop);
        float* ons_rot  = (float*)(ws + off_ons);
        int2*  entries  = (int2*)(ws + off_ent);
        int*   offsets  = (int*)(ws + off_off);
        float* pcos     = (float*)(ws + off_pc);
        float* psin     = (float*)(ws + off_ps);
        float* hop_rotT = (float*)(ws + off_hT);

        build_csr_kernel<<<1, 256, 2 * A * sizeof(int), stream>>>(edge_index, E, A,
                                                                  offsets, entries);
        phase_kernel<<<(E * K + 255) / 256, 256, 0, stream>>>(kpts, shift, pcos, psin, E, K);
        rotate_kernel<<<E + A, 128, 0, stream>>>(hop_feat, ons_feat, R, edge_index,
                                                 hop_rot, hop_rotT, ons_rot, E, A, hasT);
        const size_t shmem = (size_t)(cplx ? 2 : 1) * N * sizeof(float);
        dim3 grid((unsigned)N, (unsigned)K);
        write_kernel<<<grid, 256, shmem, stream>>>(hop_rot, hop_rotT, ons_rot,
                                                   offsets, entries, pcos, psin,
                                                   outf, A, K, cplx, hasT, lim);
    } else {
        const long long n4 = (lim + 3) / 4;
        const int zgrid = (int)((n4 + 255) / 256);
        zero_kernel<<<zgrid, 256, 0, stream>>>(outf, lim);
        edge_kernel<<<E, 256, 0, stream>>>(hop_feat, R, kpts, shift, edge_index,
                                           outf, E, A, K, cplx, lim);
        onsite_kernel<<<A, 128, 0, stream>>>(ons_feat, R, outf, A, K, cplx, lim);
    }
}